// Round 12
// baseline (173.096 us; speedup 1.0000x reference)
//
#include <hip/hip_runtime.h>
#include <cmath>

// JPEG layer, fully fused, BAND design with SMALL LOOPED CODE.
// One 256-thread WG owns a 16x256 pixel strip. Global I/O fully coalesced.
// LDS mediates pixel-major <-> block-major. The per-block codec (butterfly
// 8-pt DCT/IDCT + DPP in-register 8x8 transpose + f64-rescued quantizer)
// exists as ONE code instance inside a 3-round loop (Y row 0, Y row 1,
// chroma), and color/output phases are rolled 4-iteration loops -> static
// code ~5KB (vs ~20KB unrolled) so the body lives in L1I.

#define LEVELD 0.5019607843137255
#define LEVELF 0.5019607843137255f
#define BAND   5.0e-5f

#define CA  0.35355339059327373f
#define CB0 0.49039264020161522f
#define CB1 0.41573480615127262f
#define CB2 0.27778511650980114f
#define CB3 0.09754516100806413f
#define CC0 0.46193976625564337f
#define CC1 0.19134171618254489f

__device__ const double DMATD[64] = {
  0.3535533905932738,  0.3535533905932738,  0.3535533905932738,  0.3535533905932738,
  0.3535533905932738,  0.3535533905932738,  0.3535533905932738,  0.3535533905932738,
  0.4903926402016152,  0.4157348061512726,  0.2777851165098011,  0.0975451610080641,
 -0.0975451610080641, -0.2777851165098011, -0.4157348061512726, -0.4903926402016152,
  0.4619397662556434,  0.1913417161825449, -0.1913417161825449, -0.4619397662556434,
 -0.4619397662556434, -0.1913417161825449,  0.1913417161825449,  0.4619397662556434,
  0.4157348061512726, -0.0975451610080641, -0.4903926402016152, -0.2777851165098011,
  0.2777851165098011,  0.4903926402016152,  0.0975451610080641, -0.4157348061512726,
  0.3535533905932738, -0.3535533905932738, -0.3535533905932738,  0.3535533905932738,
  0.3535533905932738, -0.3535533905932738, -0.3535533905932738,  0.3535533905932738,
  0.2777851165098011, -0.4903926402016152,  0.0975451610080641,  0.4157348061512726,
 -0.4157348061512726, -0.0975451610080641,  0.4903926402016152, -0.2777851165098011,
  0.1913417161825449, -0.4619397662556434,  0.4619397662556434, -0.1913417161825449,
 -0.1913417161825449,  0.4619397662556434, -0.4619397662556434,  0.1913417161825449,
  0.0975451610080641, -0.2777851165098011,  0.4157348061512726, -0.4903926402016152,
  0.4903926402016152, -0.4157348061512726,  0.2777851165098011, -0.0975451610080641
};

// ---- DPP cross-lane helpers (VALU only) ----
__device__ __forceinline__ float dpp_xor1(float x) {
  return __int_as_float(__builtin_amdgcn_mov_dpp(__float_as_int(x), 0xB1, 0xF, 0xF, true));
}
__device__ __forceinline__ float dpp_xor2(float x) {
  return __int_as_float(__builtin_amdgcn_mov_dpp(__float_as_int(x), 0x4E, 0xF, 0xF, true));
}
__device__ __forceinline__ float dpp_xor4(float x) {
  int t = __builtin_amdgcn_mov_dpp(__float_as_int(x), 0x141, 0xF, 0xF, true);
  return __int_as_float(__builtin_amdgcn_mov_dpp(t, 0x1B, 0xF, 0xF, true));
}

// in-register 8x8 transpose across the 8 lanes of a group
__device__ __forceinline__ void transpose8(float v[8], int p) {
  { float t[8];
    #pragma unroll
    for (int j = 0; j < 8; ++j) t[j] = dpp_xor1(v[j ^ 1]);
    const bool lb = (p & 1) != 0;
    #pragma unroll
    for (int j = 0; j < 8; ++j) v[j] = (lb == ((j & 1) != 0)) ? v[j] : t[j];
  }
  { float t[8];
    #pragma unroll
    for (int j = 0; j < 8; ++j) t[j] = dpp_xor2(v[j ^ 2]);
    const bool lb = (p & 2) != 0;
    #pragma unroll
    for (int j = 0; j < 8; ++j) v[j] = (lb == ((j & 2) != 0)) ? v[j] : t[j];
  }
  { float t[8];
    #pragma unroll
    for (int j = 0; j < 8; ++j) t[j] = dpp_xor4(v[j ^ 4]);
    const bool lb = (p & 4) != 0;
    #pragma unroll
    for (int j = 0; j < 8; ++j) v[j] = (lb == ((j & 4) != 0)) ? v[j] : t[j];
  }
}

__device__ __forceinline__ void fdct8b(float x[8]) {
  const float s0 = x[0] + x[7], s1 = x[1] + x[6], s2 = x[2] + x[5], s3 = x[3] + x[4];
  const float d0 = x[0] - x[7], d1 = x[1] - x[6], d2 = x[2] - x[5], d3 = x[3] - x[4];
  const float t0 = s0 + s3, t1 = s1 + s2, t2 = s0 - s3, t3 = s1 - s2;
  x[0] = CA * (t0 + t1);
  x[4] = CA * (t0 - t1);
  x[2] = fmaf(CC0, t2,  CC1 * t3);
  x[6] = fmaf(CC1, t2, -CC0 * t3);
  x[1] = fmaf(CB0, d0, fmaf( CB1, d1, fmaf( CB2, d2,  CB3 * d3)));
  x[3] = fmaf(CB1, d0, fmaf(-CB3, d1, fmaf(-CB0, d2, -CB2 * d3)));
  x[5] = fmaf(CB2, d0, fmaf(-CB0, d1, fmaf( CB3, d2,  CB1 * d3)));
  x[7] = fmaf(CB3, d0, fmaf(-CB2, d1, fmaf( CB1, d2, -CB0 * d3)));
}
__device__ __forceinline__ void idct8b(float y[8]) {
  const float pe = CA * (y[0] + y[4]), qe = CA * (y[0] - y[4]);
  const float re = fmaf(CC0, y[2],  CC1 * y[6]);
  const float se = fmaf(CC1, y[2], -CC0 * y[6]);
  const float E0 = pe + re, E3 = pe - re, E1 = qe + se, E2 = qe - se;
  const float O0 = fmaf(CB0, y[1], fmaf( CB1, y[3], fmaf( CB2, y[5],  CB3 * y[7])));
  const float O1 = fmaf(CB1, y[1], fmaf(-CB3, y[3], fmaf(-CB0, y[5], -CB2 * y[7])));
  const float O2 = fmaf(CB2, y[1], fmaf(-CB0, y[3], fmaf( CB3, y[5],  CB1 * y[7])));
  const float O3 = fmaf(CB3, y[1], fmaf(-CB2, y[3], fmaf( CB1, y[5], -CB0 * y[7])));
  y[0] = E0 + O0; y[7] = E0 - O0;
  y[1] = E1 + O1; y[6] = E1 - O1;
  y[2] = E2 + O2; y[5] = E2 - O2;
  y[3] = E3 + O3; y[4] = E3 - O3;
}

// f64 recompute of rounded, dequantized coefficient (i,j). Cold path.
// mode 0 = Y (base = 8x8 block base), 1 = Cb, 2 = Cr (base = 16x16 tile base)
__device__ __attribute__((noinline)) float rescue_coef(
    const float* __restrict__ quant, const float* __restrict__ base,
    int mode, int i, int j)
{
  double acc = 0.0;
  if (mode == 0) {
    #pragma unroll 1
    for (int k = 0; k < 8; ++k) {
      double e = 0.0;
      #pragma unroll
      for (int l = 0; l < 8; ++l) {
        const size_t off = (size_t)k * 512 + l;
        const double rr = (double)base[off];
        const double gg = (double)base[262144 + off];
        const double bb = (double)base[524288 + off];
        double y = 0.299 * rr + 0.587 * gg + 0.114 * bb;
        y = fmin(fmax(y, 0.0), 1.0) - LEVELD;
        e += y * DMATD[j * 8 + l];
      }
      acc += DMATD[i * 8 + k] * e;
    }
  } else {
    const double c0 = (mode == 1) ? -0.168735892 : 0.5;
    const double c1 = (mode == 1) ? -0.331264108 : -0.418687589;
    const double c2 = (mode == 1) ?  0.5         : -0.081312411;
    #pragma unroll 1
    for (int k = 0; k < 8; ++k) {
      double e = 0.0;
      #pragma unroll 1
      for (int l = 0; l < 8; ++l) {
        double m = 0.0;
        #pragma unroll
        for (int dr = 0; dr < 2; ++dr)
          #pragma unroll
          for (int dc = 0; dc < 2; ++dc) {
            const size_t off = (size_t)(2 * k + dr) * 512 + (2 * l + dc);
            const double rr = (double)base[off];
            const double gg = (double)base[262144 + off];
            const double bb = (double)base[524288 + off];
            const double v = c0 * rr + c1 * gg + c2 * bb;
            m += fmin(fmax(v + LEVELD, 0.0), 1.0) - LEVELD;
          }
        e += (0.25 * m) * DMATD[j * 8 + l];
      }
      acc += DMATD[i * 8 + k] * e;
    }
  }
  const double qd = rint((double)quant[i * 8 + j] * 255.0) * (1.0 / 255.0);
  return (float)(rint(acc / qd) * qd);
}

#define YSTRIDE 260
#define CSTRIDE 132

__global__ __launch_bounds__(256) void jpeg_band(
    const float* __restrict__ in, const float* __restrict__ quant,
    float* __restrict__ out)
{
  __shared__ float Ylds[16 * YSTRIDE];
  __shared__ float Clds[2 * 8 * CSTRIDE];

  const int t    = threadIdx.x;
  const int wave = t >> 6;
  const int lane = t & 63;
  const int g = lane >> 3, p = lane & 7;

  const int band = blockIdx.x;               // 32 img x 32 trow x 2 halves
  const int img  = band >> 6;
  const int trow = (band >> 1) & 31;
  const int half = band & 1;
  const size_t base = (size_t)img * 786432 + (size_t)trow * 8192 + (size_t)half * 256;

  // quantizer column p (f32 exact: q*255 in [40,50]); f64 rescue arbitrates
  float qv[8], rq[8];
  #pragma unroll
  for (int i = 0; i < 8; ++i) {
    qv[i] = rintf(quant[i * 8 + p] * 255.0f) * (1.0f / 255.0f);
    rq[i] = 1.0f / qv[i];
  }

  // ========== color phase (rolled x4): coalesced load, YCC, stage ==========
  {
    const int row = t >> 4;                  // 0..15
    const int c0  = (t & 15) * 16;           // 16 px per thread
    const float* pr = in + base + (size_t)row * 512 + c0;
    float* yw = &Ylds[row * YSTRIDE + c0];
    const int crow = (row >> 1) * CSTRIDE + (c0 >> 1);
    const bool wr_c = (row & 1) == 0;

    #pragma unroll 1
    for (int i = 0; i < 4; ++i) {
      const float4 R = *(const float4*)(pr + 4 * i);
      const float4 G = *(const float4*)(pr + 262144 + 4 * i);
      const float4 B = *(const float4*)(pr + 524288 + 4 * i);

      float yv[4], cbv[4], crv[4];
      #pragma unroll
      for (int l = 0; l < 4; ++l) {
        const float rr = (&R.x)[l], gg = (&G.x)[l], bb = (&B.x)[l];
        const float y  = fmaf(0.114f, bb, fmaf(0.587f, gg, 0.299f * rr));
        const float cb = fmaf(0.5f, bb, fmaf(-0.331264108f, gg, -0.168735892f * rr));
        const float cr = fmaf(-0.081312411f, bb, fmaf(-0.418687589f, gg, 0.5f * rr));
        yv[l]  = fminf(fmaxf(y,           0.0f), 1.0f) - LEVELF;
        cbv[l] = fminf(fmaxf(cb + LEVELF, 0.0f), 1.0f) - LEVELF;
        crv[l] = fminf(fmaxf(cr + LEVELF, 0.0f), 1.0f) - LEVELF;
      }
      *(float4*)(yw + 4 * i) = make_float4(yv[0], yv[1], yv[2], yv[3]);

      // 2x2 chroma mean: horizontal in-lane, vertical via shfl_xor(16)
      float cbx = cbv[0] + cbv[1], cby = cbv[2] + cbv[3];
      float crx = crv[0] + crv[1], cry = crv[2] + crv[3];
      cbx = 0.25f * (cbx + __shfl_xor(cbx, 16));
      cby = 0.25f * (cby + __shfl_xor(cby, 16));
      crx = 0.25f * (crx + __shfl_xor(crx, 16));
      cry = 0.25f * (cry + __shfl_xor(cry, 16));
      if (wr_c) {
        *(float2*)(&Clds[crow + 2 * i])                = make_float2(cbx, cby);
        *(float2*)(&Clds[8 * CSTRIDE + crow + 2 * i])  = make_float2(crx, cry);
      }
    }
  }
  __syncthreads();

  // ========== codec rounds (ONE codec instance, looped x3) ==========
  #pragma unroll 1
  for (int r = 0; r < 3; ++r) {
    float* lp;
    const float* gb;
    int mode;
    if (r < 2) {
      const int id = r * 32 + wave * 8 + g;     // Y block id 0..63
      const int brow = id >> 5, bcol = id & 31;
      lp = &Ylds[(brow * 8 + p) * YSTRIDE + bcol * 8];
      gb = in + base + (size_t)(brow * 8) * 512 + bcol * 8;
      mode = 0;
    } else {
      const int cid = wave * 8 + g;             // 0..15 Cb, 16..31 Cr
      const int ch = cid >> 4, bc = cid & 15;
      lp = &Clds[ch * (8 * CSTRIDE) + p * CSTRIDE + bc * 8];
      gb = in + base + bc * 16;
      mode = 1 + ch;
    }

    float x[8];
    { const float4 a = *(const float4*)(lp);
      const float4 b = *(const float4*)(lp + 4);
      x[0]=a.x; x[1]=a.y; x[2]=a.z; x[3]=a.w; x[4]=b.x; x[5]=b.y; x[6]=b.z; x[7]=b.w; }

    fdct8b(x); transpose8(x, p); fdct8b(x);
    unsigned bad = 0u;
    #pragma unroll
    for (int i = 0; i < 8; ++i) {
      const float tt = x[i] * rq[i];
      const float rt = rintf(tt);
      if (fabsf(tt - rt) > 0.5f - BAND) bad |= (1u << i);
      x[i] = rt * qv[i];
    }
    if (__builtin_expect(bad != 0u, 0)) {       // cold, branched-over patch
      do {
        const int i = __builtin_ctz(bad);
        bad &= bad - 1u;
        const float fix = rescue_coef(quant, gb, mode, i, p);
        #pragma unroll
        for (int k = 0; k < 8; ++k) x[k] = (k == i) ? fix : x[k];
      } while (bad != 0u);
    }
    idct8b(x); transpose8(x, p); idct8b(x);

    *(float4*)(lp)     = make_float4(x[0], x[1], x[2], x[3]);
    *(float4*)(lp + 4) = make_float4(x[4], x[5], x[6], x[7]);
  }
  __syncthreads();

  // ========== output phase (rolled x4): upsample, YCC->RGB, store ==========
  {
    const int row = t >> 4;
    const int c0  = (t & 15) * 16;
    const float* yr = &Ylds[row * YSTRIDE + c0];
    const int crow = (row >> 1) * CSTRIDE + (c0 >> 1);
    float* po = out + base + (size_t)row * 512 + c0;

    #pragma unroll 1
    for (int i = 0; i < 4; ++i) {
      const float4 y4 = *(const float4*)(yr + 4 * i);
      const float2 cb2 = *(const float2*)(&Clds[crow + 2 * i]);
      const float2 cr2 = *(const float2*)(&Clds[8 * CSTRIDE + crow + 2 * i]);

      float RR[4], GG[4], BB[4];
      #pragma unroll
      for (int l = 0; l < 4; ++l) {
        const float y2  = (&y4.x)[l] + LEVELF;   // chroma LEVEL offsets cancel
        const float cbb = (l < 2) ? cb2.x : cb2.y;
        const float crr = (l < 2) ? cr2.x : cr2.y;
        float ro = fmaf(1.402f, crr, y2);
        float go = y2 - 0.344136286f * cbb - 0.714136286f * crr;
        float bo = fmaf(1.772f, cbb, y2);
        RR[l] = fminf(fmaxf(ro, 0.0f), 1.0f);
        GG[l] = fminf(fmaxf(go, 0.0f), 1.0f);
        BB[l] = fminf(fmaxf(bo, 0.0f), 1.0f);
      }
      *(float4*)(po + 4 * i)          = make_float4(RR[0], RR[1], RR[2], RR[3]);
      *(float4*)(po + 262144 + 4 * i) = make_float4(GG[0], GG[1], GG[2], GG[3]);
      *(float4*)(po + 524288 + 4 * i) = make_float4(BB[0], BB[1], BB[2], BB[3]);
    }
  }
}

extern "C" void kernel_launch(void* const* d_in, const int* in_sizes, int n_in,
                              void* d_out, int out_size, void* d_ws, size_t ws_size,
                              hipStream_t stream) {
  const float* in    = (const float*)d_in[0];
  const float* quant = (const float*)d_in[1];  // only quantize[0] (64 floats) used
  float* out = (float*)d_out;

  // 2048 WGs: 32 images x 32 tile-rows x 2 half-bands (16x256 px each)
  jpeg_band<<<dim3(2048), dim3(256), 0, stream>>>(in, quant, out);
}

// Round 13
// 79.712 us; speedup vs baseline: 2.1715x; 2.1715x over previous
//
#include <hip/hip_runtime.h>
#include <cmath>

// JPEG layer, fully fused. ONE WAVE PER 16x16 TILE (32768 waves = 4x CU
// oversubscription for continuous load/compute/store phase interleave).
// Lane (g=lane>>3, p=lane&7): g=0..3 -> Y 8x8 quadrant blocks (pixels straight
// to registers), g=4,5 -> Cb/Cr via tiny per-wave LDS, g=6,7 ghost (masked
// from rescue/stores). Butterfly 8-pt DCT/IDCT in-lane + DPP in-register 8x8
// transposes; call-free quantizer fast path with rare deferred f64 rescue.
// All straight-line constant-index code (R10 lesson: rolled loops -> scratch).

#define LEVELD 0.5019607843137255
#define LEVELF 0.5019607843137255f
#define BAND   5.0e-5f

#define CA  0.35355339059327373f
#define CB0 0.49039264020161522f
#define CB1 0.41573480615127262f
#define CB2 0.27778511650980114f
#define CB3 0.09754516100806413f
#define CC0 0.46193976625564337f
#define CC1 0.19134171618254489f

__device__ const double DMATD[64] = {
  0.3535533905932738,  0.3535533905932738,  0.3535533905932738,  0.3535533905932738,
  0.3535533905932738,  0.3535533905932738,  0.3535533905932738,  0.3535533905932738,
  0.4903926402016152,  0.4157348061512726,  0.2777851165098011,  0.0975451610080641,
 -0.0975451610080641, -0.2777851165098011, -0.4157348061512726, -0.4903926402016152,
  0.4619397662556434,  0.1913417161825449, -0.1913417161825449, -0.4619397662556434,
 -0.4619397662556434, -0.1913417161825449,  0.1913417161825449,  0.4619397662556434,
  0.4157348061512726, -0.0975451610080641, -0.4903926402016152, -0.2777851165098011,
  0.2777851165098011,  0.4903926402016152,  0.0975451610080641, -0.4157348061512726,
  0.3535533905932738, -0.3535533905932738, -0.3535533905932738,  0.3535533905932738,
  0.3535533905932738, -0.3535533905932738, -0.3535533905932738,  0.3535533905932738,
  0.2777851165098011, -0.4903926402016152,  0.0975451610080641,  0.4157348061512726,
 -0.4157348061512726, -0.0975451610080641,  0.4903926402016152, -0.2777851165098011,
  0.1913417161825449, -0.4619397662556434,  0.4619397662556434, -0.1913417161825449,
 -0.1913417161825449,  0.4619397662556434, -0.4619397662556434,  0.1913417161825449,
  0.0975451610080641, -0.2777851165098011,  0.4157348061512726, -0.4903926402016152,
  0.4903926402016152, -0.4157348061512726,  0.2777851165098011, -0.0975451610080641
};

// ---- DPP cross-lane helpers (VALU only) ----
__device__ __forceinline__ float dpp_xor1(float x) {  // quad_perm(1,0,3,2)
  return __int_as_float(__builtin_amdgcn_mov_dpp(__float_as_int(x), 0xB1, 0xF, 0xF, true));
}
__device__ __forceinline__ float dpp_xor2(float x) {  // quad_perm(2,3,0,1)
  return __int_as_float(__builtin_amdgcn_mov_dpp(__float_as_int(x), 0x4E, 0xF, 0xF, true));
}
__device__ __forceinline__ float dpp_xor4(float x) {  // half_mirror o quad_mirror
  int t = __builtin_amdgcn_mov_dpp(__float_as_int(x), 0x141, 0xF, 0xF, true);
  return __int_as_float(__builtin_amdgcn_mov_dpp(t, 0x1B, 0xF, 0xF, true));
}

// in-register 8x8 transpose across the 8 lanes of a group; v[j]@p -> v[p]@j
__device__ __forceinline__ void transpose8(float v[8], int p) {
  { float t[8];
    #pragma unroll
    for (int j = 0; j < 8; ++j) t[j] = dpp_xor1(v[j ^ 1]);
    const bool lb = (p & 1) != 0;
    #pragma unroll
    for (int j = 0; j < 8; ++j) v[j] = (lb == ((j & 1) != 0)) ? v[j] : t[j];
  }
  { float t[8];
    #pragma unroll
    for (int j = 0; j < 8; ++j) t[j] = dpp_xor2(v[j ^ 2]);
    const bool lb = (p & 2) != 0;
    #pragma unroll
    for (int j = 0; j < 8; ++j) v[j] = (lb == ((j & 2) != 0)) ? v[j] : t[j];
  }
  { float t[8];
    #pragma unroll
    for (int j = 0; j < 8; ++j) t[j] = dpp_xor4(v[j ^ 4]);
    const bool lb = (p & 4) != 0;
    #pragma unroll
    for (int j = 0; j < 8; ++j) v[j] = (lb == ((j & 4) != 0)) ? v[j] : t[j];
  }
}

// forward 8-pt DCT (y = D x), butterflied
__device__ __forceinline__ void fdct8b(float x[8]) {
  const float s0 = x[0] + x[7], s1 = x[1] + x[6], s2 = x[2] + x[5], s3 = x[3] + x[4];
  const float d0 = x[0] - x[7], d1 = x[1] - x[6], d2 = x[2] - x[5], d3 = x[3] - x[4];
  const float t0 = s0 + s3, t1 = s1 + s2, t2 = s0 - s3, t3 = s1 - s2;
  x[0] = CA * (t0 + t1);
  x[4] = CA * (t0 - t1);
  x[2] = fmaf(CC0, t2,  CC1 * t3);
  x[6] = fmaf(CC1, t2, -CC0 * t3);
  x[1] = fmaf(CB0, d0, fmaf( CB1, d1, fmaf( CB2, d2,  CB3 * d3)));
  x[3] = fmaf(CB1, d0, fmaf(-CB3, d1, fmaf(-CB0, d2, -CB2 * d3)));
  x[5] = fmaf(CB2, d0, fmaf(-CB0, d1, fmaf( CB3, d2,  CB1 * d3)));
  x[7] = fmaf(CB3, d0, fmaf(-CB2, d1, fmaf( CB1, d2, -CB0 * d3)));
}
// inverse 8-pt DCT (o = D^T y), butterflied
__device__ __forceinline__ void idct8b(float y[8]) {
  const float pe = CA * (y[0] + y[4]), qe = CA * (y[0] - y[4]);
  const float re = fmaf(CC0, y[2],  CC1 * y[6]);
  const float se = fmaf(CC1, y[2], -CC0 * y[6]);
  const float E0 = pe + re, E3 = pe - re, E1 = qe + se, E2 = qe - se;
  const float O0 = fmaf(CB0, y[1], fmaf( CB1, y[3], fmaf( CB2, y[5],  CB3 * y[7])));
  const float O1 = fmaf(CB1, y[1], fmaf(-CB3, y[3], fmaf(-CB0, y[5], -CB2 * y[7])));
  const float O2 = fmaf(CB2, y[1], fmaf(-CB0, y[3], fmaf( CB3, y[5],  CB1 * y[7])));
  const float O3 = fmaf(CB3, y[1], fmaf(-CB2, y[3], fmaf( CB1, y[5], -CB0 * y[7])));
  y[0] = E0 + O0; y[7] = E0 - O0;
  y[1] = E1 + O1; y[6] = E1 - O1;
  y[2] = E2 + O2; y[5] = E2 - O2;
  y[3] = E3 + O3; y[4] = E3 - O3;
}

// f64 recompute of rounded, dequantized coefficient (i,j). Cold path.
// mode 0 = Y (base = 8x8 block base), 1 = Cb, 2 = Cr (base = 16x16 tile base)
__device__ __attribute__((noinline)) float rescue_coef(
    const float* __restrict__ quant, const float* __restrict__ base,
    int mode, int i, int j)
{
  double acc = 0.0;
  if (mode == 0) {
    #pragma unroll 1
    for (int k = 0; k < 8; ++k) {
      double e = 0.0;
      #pragma unroll
      for (int l = 0; l < 8; ++l) {
        const size_t off = (size_t)k * 512 + l;
        const double rr = (double)base[off];
        const double gg = (double)base[262144 + off];
        const double bb = (double)base[524288 + off];
        double y = 0.299 * rr + 0.587 * gg + 0.114 * bb;
        y = fmin(fmax(y, 0.0), 1.0) - LEVELD;
        e += y * DMATD[j * 8 + l];
      }
      acc += DMATD[i * 8 + k] * e;
    }
  } else {
    const double c0 = (mode == 1) ? -0.168735892 : 0.5;
    const double c1 = (mode == 1) ? -0.331264108 : -0.418687589;
    const double c2 = (mode == 1) ?  0.5         : -0.081312411;
    #pragma unroll 1
    for (int k = 0; k < 8; ++k) {
      double e = 0.0;
      #pragma unroll 1
      for (int l = 0; l < 8; ++l) {
        double m = 0.0;
        #pragma unroll
        for (int dr = 0; dr < 2; ++dr)
          #pragma unroll
          for (int dc = 0; dc < 2; ++dc) {
            const size_t off = (size_t)(2 * k + dr) * 512 + (2 * l + dc);
            const double rr = (double)base[off];
            const double gg = (double)base[262144 + off];
            const double bb = (double)base[524288 + off];
            const double v = c0 * rr + c1 * gg + c2 * bb;
            m += fmin(fmax(v + LEVELD, 0.0), 1.0) - LEVELD;
          }
        e += (0.25 * m) * DMATD[j * 8 + l];
      }
      acc += DMATD[i * 8 + k] * e;
    }
  }
  const double qd = rint((double)quant[i * 8 + j] * 255.0) * (1.0 / 255.0);
  return (float)(rint(acc / qd) * qd);
}

__global__ __launch_bounds__(64) void jpeg_fused(
    const float* __restrict__ in, const float* __restrict__ quant,
    float* __restrict__ out)
{
  __shared__ float CH[136];   // [cb 68 | cr 68] swizzle-free per-wave buffer

  const int lane = threadIdx.x;
  const int g = lane >> 3, p = lane & 7;
  const int qr = (g >> 1) & 1, qc = g & 1;

  const int u    = blockIdx.x;                // one 16x16 tile
  const int img  = u >> 10;
  const int trow = (u >> 5) & 31;
  const int tcol = u & 31;
  const size_t tbase = (size_t)img * 786432 + (size_t)trow * 8192 + (size_t)tcol * 16;
  const float* tb = in + tbase;

  // ---- hoisted pixel loads: row p of Y block (qr,qc) ----
  const float* pb = tb + (size_t)(qr * 8 + p) * 512 + qc * 8;
  const float4 R0 = *(const float4*)(pb);
  const float4 R1 = *(const float4*)(pb + 4);
  const float4 G0 = *(const float4*)(pb + 262144);
  const float4 G1 = *(const float4*)(pb + 262148);
  const float4 B0 = *(const float4*)(pb + 524288);
  const float4 B1 = *(const float4*)(pb + 524292);

  // quantizer column p (f32 exact: q*255 in [40,50]); f64 rescue arbitrates
  float qv[8], rq[8];
  #pragma unroll
  for (int i = 0; i < 8; ++i) {
    qv[i] = rintf(quant[i * 8 + p] * 255.0f) * (1.0f / 255.0f);
    rq[i] = 1.0f / qv[i];
  }

  // ---- color + chroma-mean staging (g<4 lanes carry real pixel data) ----
  const float RL[8] = {R0.x, R0.y, R0.z, R0.w, R1.x, R1.y, R1.z, R1.w};
  const float GL[8] = {G0.x, G0.y, G0.z, G0.w, G1.x, G1.y, G1.z, G1.w};
  const float BL[8] = {B0.x, B0.y, B0.z, B0.w, B1.x, B1.y, B1.z, B1.w};

  float x[8], cbv[8], crv[8];
  #pragma unroll
  for (int l = 0; l < 8; ++l) {
    const float rr = RL[l], gg = GL[l], bb = BL[l];
    const float y  = fmaf(0.114f, bb, fmaf(0.587f, gg, 0.299f * rr));
    const float cb = fmaf(0.5f, bb, fmaf(-0.331264108f, gg, -0.168735892f * rr));
    const float cr = fmaf(-0.081312411f, bb, fmaf(-0.418687589f, gg, 0.5f * rr));
    x[l]   = fminf(fmaxf(y,           0.0f), 1.0f) - LEVELF;
    cbv[l] = fminf(fmaxf(cb + LEVELF, 0.0f), 1.0f) - LEVELF;
    crv[l] = fminf(fmaxf(cr + LEVELF, 0.0f), 1.0f) - LEVELF;
  }
  // 2x2 chroma mean: horizontal in-lane, vertical via DPP xor1 (rows p, p^1)
  float ch[4];
  #pragma unroll
  for (int j = 0; j < 4; ++j) {
    const float cbh = cbv[2 * j] + cbv[2 * j + 1];
    const float crh = crv[2 * j] + crv[2 * j + 1];
    const float cbs = cbh + dpp_xor1(cbh);
    const float crs = crh + dpp_xor1(crh);
    ch[j] = 0.25f * ((p & 1) ? crs : cbs);   // even lanes: cb, odd: cr
  }
  if (g < 4) {
    float* dst = &CH[(p & 1) * 68 + (qr * 4 + (p >> 1)) * 8 + qc * 4];
    *(float4*)dst = make_float4(ch[0], ch[1], ch[2], ch[3]);
  }
  __builtin_amdgcn_wave_barrier();

  if (g >= 4) {   // chroma lanes (and ghosts g=6,7): row p of Cb/Cr from LDS
    const float* src = &CH[(g & 1) * 68 + p * 8];
    const float4 a = *(const float4*)(src);
    const float4 b = *(const float4*)(src + 4);
    x[0] = a.x; x[1] = a.y; x[2] = a.z; x[3] = a.w;
    x[4] = b.x; x[5] = b.y; x[6] = b.z; x[7] = b.w;
  }
  __builtin_amdgcn_wave_barrier();

  // ---- codec: DCT -> quantize (call-free; deferred f64 rescue) -> IDCT ----
  fdct8b(x); transpose8(x, p); fdct8b(x);
  unsigned bad = 0u;
  #pragma unroll
  for (int i = 0; i < 8; ++i) {
    const float tt = x[i] * rq[i];
    const float rt = rintf(tt);
    if (fabsf(tt - rt) > 0.5f - BAND) bad |= (1u << i);
    x[i] = rt * qv[i];
  }
  if (g >= 6) bad = 0u;                       // ghost lanes never rescue
  if (__builtin_expect(bad != 0u, 0)) {       // cold, branched-over patch
    const int mode = (g < 4) ? 0 : (g == 4 ? 1 : 2);
    const float* gbase = (g < 4) ? (tb + (size_t)(qr * 8) * 512 + qc * 8) : tb;
    do {
      const int i = __builtin_ctz(bad);
      bad &= bad - 1u;
      const float fix = rescue_coef(quant, gbase, mode, i, p);
      #pragma unroll
      for (int k = 0; k < 8; ++k) x[k] = (k == i) ? fix : x[k];
    } while (bad != 0u);
  }
  idct8b(x); transpose8(x, p); idct8b(x);

  // chroma results back to LDS for upsampling
  if ((g & 6) == 4) {   // g == 4 or 5
    float* dst = &CH[(g & 1) * 68 + p * 8];
    *(float4*)(dst)     = make_float4(x[0], x[1], x[2], x[3]);
    *(float4*)(dst + 4) = make_float4(x[4], x[5], x[6], x[7]);
  }
  __builtin_amdgcn_wave_barrier();

  // ---- output: upsample chroma, YCC->RGB, clamp, store (g<4 lanes) ----
  if (g < 4) {
    const float* cbp = &CH[(qr * 4 + (p >> 1)) * 8 + qc * 4];
    const float4 cb4 = *(const float4*)(cbp);
    const float4 cr4 = *(const float4*)(cbp + 68);
    const float cba[4] = {cb4.x, cb4.y, cb4.z, cb4.w};
    const float cra[4] = {cr4.x, cr4.y, cr4.z, cr4.w};

    float RR[8], GG[8], BB[8];
    #pragma unroll
    for (int l = 0; l < 8; ++l) {
      const float y2 = x[l] + LEVELF;        // chroma LEVEL offsets cancel
      const float cbb = cba[l >> 1], crr = cra[l >> 1];
      float ro = fmaf(1.402f, crr, y2);
      float go = y2 - 0.344136286f * cbb - 0.714136286f * crr;
      float bo = fmaf(1.772f, cbb, y2);
      RR[l] = fminf(fmaxf(ro, 0.0f), 1.0f);
      GG[l] = fminf(fmaxf(go, 0.0f), 1.0f);
      BB[l] = fminf(fmaxf(bo, 0.0f), 1.0f);
    }
    float* ob = out + tbase + (size_t)(qr * 8 + p) * 512 + qc * 8;
    *(float4*)(ob)              = make_float4(RR[0], RR[1], RR[2], RR[3]);
    *(float4*)(ob + 4)          = make_float4(RR[4], RR[5], RR[6], RR[7]);
    *(float4*)(ob + 262144)     = make_float4(GG[0], GG[1], GG[2], GG[3]);
    *(float4*)(ob + 262148)     = make_float4(GG[4], GG[5], GG[6], GG[7]);
    *(float4*)(ob + 524288)     = make_float4(BB[0], BB[1], BB[2], BB[3]);
    *(float4*)(ob + 524292)     = make_float4(BB[4], BB[5], BB[6], BB[7]);
  }
}

extern "C" void kernel_launch(void* const* d_in, const int* in_sizes, int n_in,
                              void* d_out, int out_size, void* d_ws, size_t ws_size,
                              hipStream_t stream) {
  const float* in    = (const float*)d_in[0];
  const float* quant = (const float*)d_in[1];  // only quantize[0] (64 floats) used
  float* out = (float*)d_out;

  // 32768 single-wave WGs: one 16x16 tile each (4x CU oversubscription)
  jpeg_fused<<<dim3(32768), dim3(64), 0, stream>>>(in, quant, out);
}

// Round 15
// 63.249 us; speedup vs baseline: 2.7367x; 1.2603x over previous
//
#include <hip/hip_runtime.h>
#include <cmath>

// JPEG layer, fully fused. One wave (= one 64-thread workgroup) handles 4
// horizontally-consecutive 16x16 tiles: 16 Y blocks + 4 Cb + 4 Cr = 24 blocks
// in 3 full-lane transform rounds. Lane (g = lane>>3, p = lane&7) owns row p
// of block-slot g. Butterfly 8-pt DCT/IDCT in-lane + DPP in-register 8x8
// transposes. All global loads hoisted to the kernel top; quantizer fast path
// is call-free with a deferred f64 rescue patch.
// R13 change vs R6 champion: output stores are NON-TEMPORAL (stream past
// L2/L3) to stop the 98MB write stream from evicting the L3-resident input.
// (R12 compile fix: use clang ext_vector_type, not HIP float4, for the NT
// store builtin.)

#define LEVELD 0.5019607843137255
#define LEVELF 0.5019607843137255f
#define BAND   5.0e-5f

#define CA  0.35355339059327373f
#define CB0 0.49039264020161522f
#define CB1 0.41573480615127262f
#define CB2 0.27778511650980114f
#define CB3 0.09754516100806413f
#define CC0 0.46193976625564337f
#define CC1 0.19134171618254489f

typedef float v4f __attribute__((ext_vector_type(4)));

__device__ __forceinline__ void nt_store4(float* p, float a, float b, float c, float d) {
  v4f v = {a, b, c, d};
  __builtin_nontemporal_store(v, (v4f*)p);
}

__device__ const double DMATD[64] = {
  0.3535533905932738,  0.3535533905932738,  0.3535533905932738,  0.3535533905932738,
  0.3535533905932738,  0.3535533905932738,  0.3535533905932738,  0.3535533905932738,
  0.4903926402016152,  0.4157348061512726,  0.2777851165098011,  0.0975451610080641,
 -0.0975451610080641, -0.2777851165098011, -0.4157348061512726, -0.4903926402016152,
  0.4619397662556434,  0.1913417161825449, -0.1913417161825449, -0.4619397662556434,
 -0.4619397662556434, -0.1913417161825449,  0.1913417161825449,  0.4619397662556434,
  0.4157348061512726, -0.0975451610080641, -0.4903926402016152, -0.2777851165098011,
  0.2777851165098011,  0.4903926402016152,  0.0975451610080641, -0.4157348061512726,
  0.3535533905932738, -0.3535533905932738, -0.3535533905932738,  0.3535533905932738,
  0.3535533905932738, -0.3535533905932738, -0.3535533905932738,  0.3535533905932738,
  0.2777851165098011, -0.4903926402016152,  0.0975451610080641,  0.4157348061512726,
 -0.4157348061512726, -0.0975451610080641,  0.4903926402016152, -0.2777851165098011,
  0.1913417161825449, -0.4619397662556434,  0.4619397662556434, -0.1913417161825449,
 -0.1913417161825449,  0.4619397662556434, -0.4619397662556434,  0.1913417161825449,
  0.0975451610080641, -0.2777851165098011,  0.4157348061512726, -0.4903926402016152,
  0.4903926402016152, -0.4157348061512726,  0.2777851165098011, -0.0975451610080641
};

// ---- DPP cross-lane helpers (VALU only) ----
__device__ __forceinline__ float dpp_xor1(float x) {  // quad_perm(1,0,3,2)
  return __int_as_float(__builtin_amdgcn_mov_dpp(__float_as_int(x), 0xB1, 0xF, 0xF, true));
}
__device__ __forceinline__ float dpp_xor2(float x) {  // quad_perm(2,3,0,1)
  return __int_as_float(__builtin_amdgcn_mov_dpp(__float_as_int(x), 0x4E, 0xF, 0xF, true));
}
__device__ __forceinline__ float dpp_xor4(float x) {  // half_mirror o quad_mirror
  int t = __builtin_amdgcn_mov_dpp(__float_as_int(x), 0x141, 0xF, 0xF, true);
  return __int_as_float(__builtin_amdgcn_mov_dpp(t, 0x1B, 0xF, 0xF, true));
}

// in-register 8x8 transpose across the 8 lanes of a group; v[j]@p -> v[p]@j
__device__ __forceinline__ void transpose8(float v[8], int p) {
  { float t[8];
    #pragma unroll
    for (int j = 0; j < 8; ++j) t[j] = dpp_xor1(v[j ^ 1]);
    const bool lb = (p & 1) != 0;
    #pragma unroll
    for (int j = 0; j < 8; ++j) v[j] = (lb == ((j & 1) != 0)) ? v[j] : t[j];
  }
  { float t[8];
    #pragma unroll
    for (int j = 0; j < 8; ++j) t[j] = dpp_xor2(v[j ^ 2]);
    const bool lb = (p & 2) != 0;
    #pragma unroll
    for (int j = 0; j < 8; ++j) v[j] = (lb == ((j & 2) != 0)) ? v[j] : t[j];
  }
  { float t[8];
    #pragma unroll
    for (int j = 0; j < 8; ++j) t[j] = dpp_xor4(v[j ^ 4]);
    const bool lb = (p & 4) != 0;
    #pragma unroll
    for (int j = 0; j < 8; ++j) v[j] = (lb == ((j & 4) != 0)) ? v[j] : t[j];
  }
}

// forward 8-pt DCT (y = D x), butterflied
__device__ __forceinline__ void fdct8b(float x[8]) {
  const float s0 = x[0] + x[7], s1 = x[1] + x[6], s2 = x[2] + x[5], s3 = x[3] + x[4];
  const float d0 = x[0] - x[7], d1 = x[1] - x[6], d2 = x[2] - x[5], d3 = x[3] - x[4];
  const float t0 = s0 + s3, t1 = s1 + s2, t2 = s0 - s3, t3 = s1 - s2;
  x[0] = CA * (t0 + t1);
  x[4] = CA * (t0 - t1);
  x[2] = fmaf(CC0, t2,  CC1 * t3);
  x[6] = fmaf(CC1, t2, -CC0 * t3);
  x[1] = fmaf(CB0, d0, fmaf( CB1, d1, fmaf( CB2, d2,  CB3 * d3)));
  x[3] = fmaf(CB1, d0, fmaf(-CB3, d1, fmaf(-CB0, d2, -CB2 * d3)));
  x[5] = fmaf(CB2, d0, fmaf(-CB0, d1, fmaf( CB3, d2,  CB1 * d3)));
  x[7] = fmaf(CB3, d0, fmaf(-CB2, d1, fmaf( CB1, d2, -CB0 * d3)));
}
// inverse 8-pt DCT (o = D^T y), butterflied
__device__ __forceinline__ void idct8b(float y[8]) {
  const float pe = CA * (y[0] + y[4]), qe = CA * (y[0] - y[4]);
  const float re = fmaf(CC0, y[2],  CC1 * y[6]);
  const float se = fmaf(CC1, y[2], -CC0 * y[6]);
  const float E0 = pe + re, E3 = pe - re, E1 = qe + se, E2 = qe - se;
  const float O0 = fmaf(CB0, y[1], fmaf( CB1, y[3], fmaf( CB2, y[5],  CB3 * y[7])));
  const float O1 = fmaf(CB1, y[1], fmaf(-CB3, y[3], fmaf(-CB0, y[5], -CB2 * y[7])));
  const float O2 = fmaf(CB2, y[1], fmaf(-CB0, y[3], fmaf( CB3, y[5],  CB1 * y[7])));
  const float O3 = fmaf(CB3, y[1], fmaf(-CB2, y[3], fmaf( CB1, y[5], -CB0 * y[7])));
  y[0] = E0 + O0; y[7] = E0 - O0;
  y[1] = E1 + O1; y[6] = E1 - O1;
  y[2] = E2 + O2; y[5] = E2 - O2;
  y[3] = E3 + O3; y[4] = E3 - O3;
}

// f64 recompute of dequantized coefficient (i,j). mode 0 = Y (base = 8x8
// block base), mode 1 = Cb, mode 2 = Cr (base = 16x16 tile base). Cold.
__device__ __attribute__((noinline)) float rescue_coef(
    const float* __restrict__ quant, const float* __restrict__ base,
    int mode, int i, int j)
{
  double acc = 0.0;
  if (mode == 0) {
    #pragma unroll 1
    for (int k = 0; k < 8; ++k) {
      double e = 0.0;
      #pragma unroll
      for (int l = 0; l < 8; ++l) {
        const size_t off = (size_t)k * 512 + l;
        const double rr = (double)base[off];
        const double gg = (double)base[262144 + off];
        const double bb = (double)base[524288 + off];
        double y = 0.299 * rr + 0.587 * gg + 0.114 * bb;
        y = fmin(fmax(y, 0.0), 1.0) - LEVELD;
        e += y * DMATD[j * 8 + l];
      }
      acc += DMATD[i * 8 + k] * e;
    }
  } else {
    const double c0 = (mode == 1) ? -0.168735892 : 0.5;
    const double c1 = (mode == 1) ? -0.331264108 : -0.418687589;
    const double c2 = (mode == 1) ?  0.5         : -0.081312411;
    #pragma unroll 1
    for (int k = 0; k < 8; ++k) {
      double e = 0.0;
      #pragma unroll 1
      for (int l = 0; l < 8; ++l) {
        double m = 0.0;
        #pragma unroll
        for (int dr = 0; dr < 2; ++dr)
          #pragma unroll
          for (int dc = 0; dc < 2; ++dc) {
            const size_t off = (size_t)(2 * k + dr) * 512 + (2 * l + dc);
            const double rr = (double)base[off];
            const double gg = (double)base[262144 + off];
            const double bb = (double)base[524288 + off];
            const double v = c0 * rr + c1 * gg + c2 * bb;
            m += fmin(fmax(v + LEVELD, 0.0), 1.0) - LEVELD;
          }
        e += (0.25 * m) * DMATD[j * 8 + l];
      }
      acc += DMATD[i * 8 + k] * e;
    }
  }
  const double qd = rint((double)quant[i * 8 + j] * 255.0) * (1.0 / 255.0);
  return (float)(rint(acc / qd) * qd);
}

// per-block codec: DCT -> quant(round; deferred f64 rescue) -> IDCT, in place
__device__ __forceinline__ void codec8(float x[8], const float qv[8], const float rq[8],
                                       int p, int mode, const float* __restrict__ base,
                                       const float* __restrict__ quant)
{
  fdct8b(x); transpose8(x, p); fdct8b(x);
  unsigned bad = 0u;
  #pragma unroll
  for (int i = 0; i < 8; ++i) {
    const float tt = x[i] * rq[i];
    const float rt = rintf(tt);
    if (fabsf(tt - rt) > 0.5f - BAND) bad |= (1u << i);
    x[i] = rt * qv[i];
  }
  if (__builtin_expect(bad != 0u, 0)) {     // cold, branched-over patch
    do {
      const int i = __builtin_ctz(bad);
      bad &= bad - 1u;
      const float fix = rescue_coef(quant, base, mode, i, p);
      #pragma unroll
      for (int k = 0; k < 8; ++k) x[k] = (k == i) ? fix : x[k];
    } while (bad != 0u);
  }
  idct8b(x); transpose8(x, p); idct8b(x);
}

// color + chroma-mean staging for one Y round (loads already in registers)
__device__ __forceinline__ void color_stage(
    const float4 L6[6], int tY, int qr, int qc, int p,
    float4* __restrict__ CHW, float rout[8])
{
  const float RL[8] = {L6[0].x, L6[0].y, L6[0].z, L6[0].w, L6[1].x, L6[1].y, L6[1].z, L6[1].w};
  const float GL[8] = {L6[2].x, L6[2].y, L6[2].z, L6[2].w, L6[3].x, L6[3].y, L6[3].z, L6[3].w};
  const float BL[8] = {L6[4].x, L6[4].y, L6[4].z, L6[4].w, L6[5].x, L6[5].y, L6[5].z, L6[5].w};

  float cbv[8], crv[8];
  #pragma unroll
  for (int l = 0; l < 8; ++l) {
    const float rr = RL[l], gg = GL[l], bb = BL[l];
    const float y  = fmaf(0.114f, bb, fmaf(0.587f, gg, 0.299f * rr));
    const float cb = fmaf(0.5f, bb, fmaf(-0.331264108f, gg, -0.168735892f * rr));
    const float cr = fmaf(-0.081312411f, bb, fmaf(-0.418687589f, gg, 0.5f * rr));
    rout[l] = fminf(fmaxf(y,           0.0f), 1.0f) - LEVELF;
    cbv[l]  = fminf(fmaxf(cb + LEVELF, 0.0f), 1.0f) - LEVELF;
    crv[l]  = fminf(fmaxf(cr + LEVELF, 0.0f), 1.0f) - LEVELF;
  }
  float ch[4];
  #pragma unroll
  for (int j = 0; j < 4; ++j) {
    const float cbh = cbv[2 * j] + cbv[2 * j + 1];
    const float crh = crv[2 * j] + crv[2 * j + 1];
    const float cbs = cbh + dpp_xor1(cbh);
    const float crs = crh + dpp_xor1(crh);
    ch[j] = 0.25f * ((p & 1) ? crs : cbs);   // even lanes: cb, odd: cr
  }
  const int crow = qr * 4 + (p >> 1);
  const int slot = ((((p & 1) * 4 + tY) * 16) + crow * 2 + qc) ^ ((tY << 1) | qr);
  CHW[slot] = make_float4(ch[0], ch[1], ch[2], ch[3]);
}

// upsample chroma from LDS, YCC->RGB, clamp, nontemporal store one Y round
__device__ __forceinline__ void out_phase(
    float* __restrict__ ob, int tY, int qr, int qc, int p,
    const float4* __restrict__ CHW, const float r[8])
{
  const int crow = qr * 4 + (p >> 1);
  const int swz = (tY << 1) | qr;
  const float4 cb4 = CHW[((tY * 16) + crow * 2 + qc) ^ swz];
  const float4 cr4 = CHW[(((4 + tY) * 16) + crow * 2 + qc) ^ swz];
  const float cba[4] = {cb4.x, cb4.y, cb4.z, cb4.w};
  const float cra[4] = {cr4.x, cr4.y, cr4.z, cr4.w};

  float RR[8], GG[8], BB[8];
  #pragma unroll
  for (int l = 0; l < 8; ++l) {
    const float y2 = r[l] + LEVELF;          // chroma LEVEL offsets cancel
    const float cbb = cba[l >> 1], crr = cra[l >> 1];
    float ro = fmaf(1.402f, crr, y2);
    float go = y2 - 0.344136286f * cbb - 0.714136286f * crr;
    float bo = fmaf(1.772f, cbb, y2);
    RR[l] = fminf(fmaxf(ro, 0.0f), 1.0f);
    GG[l] = fminf(fmaxf(go, 0.0f), 1.0f);
    BB[l] = fminf(fmaxf(bo, 0.0f), 1.0f);
  }
  float* op = ob + (size_t)(qr * 8 + p) * 512 + tY * 16 + qc * 8;
  nt_store4(op,              RR[0], RR[1], RR[2], RR[3]);
  nt_store4(op + 4,          RR[4], RR[5], RR[6], RR[7]);
  nt_store4(op + 262144,     GG[0], GG[1], GG[2], GG[3]);
  nt_store4(op + 262148,     GG[4], GG[5], GG[6], GG[7]);
  nt_store4(op + 524288,     BB[0], BB[1], BB[2], BB[3]);
  nt_store4(op + 524292,     BB[4], BB[5], BB[6], BB[7]);
}

__global__ __launch_bounds__(64, 4) void jpeg_fused(
    const float* __restrict__ in, const float* __restrict__ quant,
    float* __restrict__ out)
{
  __shared__ float4 CH[128];   // 8 chroma blocks (swizzled slots), 2 KiB

  const int lane = threadIdx.x;
  const int g = lane >> 3, p = lane & 7;
  const int tx = g >> 2, qr = (g >> 1) & 1, qc = g & 1;

  const int u    = blockIdx.x;                // unit = 4 tiles in a row
  const int img  = u >> 8;
  const int trow = (u >> 3) & 31;
  const int tcq  = u & 7;
  const size_t tboff = (size_t)img * 786432 + (size_t)trow * 16 * 512 + (size_t)tcq * 64;
  const float* tb = in + tboff;
  float* ob = out + tboff;

  // ---- hoisted global loads: both Y rounds' pixels + quant column ----
  float4 L[2][6];
  #pragma unroll
  for (int h = 0; h < 2; ++h) {
    const int tY = 2 * h + tx;
    const float* pb = tb + (size_t)(qr * 8 + p) * 512 + tY * 16 + qc * 8;
    L[h][0] = *(const float4*)(pb);
    L[h][1] = *(const float4*)(pb + 4);
    L[h][2] = *(const float4*)(pb + 262144);
    L[h][3] = *(const float4*)(pb + 262148);
    L[h][4] = *(const float4*)(pb + 524288);
    L[h][5] = *(const float4*)(pb + 524292);
  }
  float qf[8];
  #pragma unroll
  for (int i = 0; i < 8; ++i) qf[i] = quant[i * 8 + p];

  // quantizer column p in f32: rintf(q*255) is exact (q*255 in [40,50]);
  // <=1-ulp dequant difference vs f64, arbitrated by the f64 rescue anyway
  float qv[8], rq[8];
  #pragma unroll
  for (int i = 0; i < 8; ++i) {
    qv[i] = rintf(qf[i] * 255.0f) * (1.0f / 255.0f);
    rq[i] = 1.0f / qv[i];
  }

  // ---- color + chroma staging for both rounds ----
  float rA[8], rB[8];
  color_stage(L[0], 2 * 0 + tx, qr, qc, p, CH, rA);
  color_stage(L[1], 2 * 1 + tx, qr, qc, p, CH, rB);
  __builtin_amdgcn_wave_barrier();

  // ---- Y codecs (call-free fast path) ----
  const float* blkA = tb + (size_t)(qr * 8) * 512 + (2 * 0 + tx) * 16 + qc * 8;
  const float* blkB = tb + (size_t)(qr * 8) * 512 + (2 * 1 + tx) * 16 + qc * 8;
  codec8(rA, qv, rq, p, 0, blkA, quant);
  codec8(rB, qv, rq, p, 0, blkB, quant);

  // ---- chroma codec round: 8 blocks (g>>2: 0=Cb,1=Cr; g&3: unit tile) ----
  {
    const int cpar = g >> 2, ct = g & 3;
    const int pre  = (cpar * 4 + ct) * 16 + p * 2;
    const int swz  = (ct << 1) | (p >> 2);
    const int sl = pre ^ swz, sh = (pre + 1) ^ swz;
    const float4 a = CH[sl];
    const float4 b = CH[sh];
    float xc[8] = {a.x, a.y, a.z, a.w, b.x, b.y, b.z, b.w};
    codec8(xc, qv, rq, p, 1 + cpar, tb + ct * 16, quant);
    CH[sl] = make_float4(xc[0], xc[1], xc[2], xc[3]);
    CH[sh] = make_float4(xc[4], xc[5], xc[6], xc[7]);
  }
  __builtin_amdgcn_wave_barrier();

  // ---- output both rounds (non-temporal stores) ----
  out_phase(ob, 2 * 0 + tx, qr, qc, p, CH, rA);
  out_phase(ob, 2 * 1 + tx, qr, qc, p, CH, rB);
}

extern "C" void kernel_launch(void* const* d_in, const int* in_sizes, int n_in,
                              void* d_out, int out_size, void* d_ws, size_t ws_size,
                              hipStream_t stream) {
  const float* in    = (const float*)d_in[0];
  const float* quant = (const float*)d_in[1];  // only quantize[0] (64 floats) used
  float* out = (float*)d_out;

  // 8192 single-wave workgroups (32 img x 32 trow x 8 four-tile units)
  jpeg_fused<<<dim3(8192), dim3(64), 0, stream>>>(in, quant, out);
}